// Round 10
// baseline (388.934 us; speedup 1.0000x reference)
//
#include <hip/hip_runtime.h>
#include <hip/hip_fp16.h>

#define N_USER 50000
#define N_ITEM 100000
#define NTOT   150000          // N_USER + N_ITEM
#define NNZ    3000000
#define EMB    64
#define BATCH  4096

#define NB     586             // buckets of 256 rows: ceil(150000/256)
#define BCAP   5632            // mean 5119, sd ~72 -> +7 sigma
#define CHUNK  3072            // edges per k_bucket block (977 blocks, 3.8/CU)
#define SSTR   67              // LDS side-tile row stride (words), odd -> bank-rotating

#define SCALE  262144.0f       // 2^18 fixed-point scale
#define INVSC  (1.0f / 262144.0f)

typedef unsigned short u16;
typedef unsigned int   u32;
typedef _Float16 f16;
typedef f16   f16x8 __attribute__((ext_vector_type(8)));
typedef float f32x4 __attribute__((ext_vector_type(4)));

// ---------------------------------------------------------------------------
// ego(f16) = concat(user_emb, item_emb)
// ---------------------------------------------------------------------------
__global__ __launch_bounds__(256) void k_init_ego(const float4* __restrict__ ue,
                                                  const float4* __restrict__ ie,
                                                  uint2* __restrict__ ego) {
    int i = blockIdx.x * 256 + threadIdx.x;
    const int UF4 = N_USER * EMB / 4;     // 800000
    float4 f = (i < UF4) ? ue[i] : ie[i - UF4];
    __half2 h0 = __floats2half2_rn(f.x, f.y);
    __half2 h1 = __floats2half2_rn(f.z, f.w);
    ego[i] = make_uint2(*(u32*)&h0, *(u32*)&h1);
}

// ---------------------------------------------------------------------------
// out[i][:] = user_emb[users[i]][:]   (layer-0 contribution, exact fp32)
// ---------------------------------------------------------------------------
__global__ __launch_bounds__(256) void k_init_out(const float* __restrict__ ue,
                                                  const int* __restrict__ users,
                                                  float* __restrict__ out) {
    int t = blockIdx.x * 256 + threadIdx.x;
    int w = t >> 6, lane = t & 63;
    int u = users[w];
    out[w * EMB + lane] = ue[(size_t)u * EMB + lane];
}

// ---------------------------------------------------------------------------
// Bucket edges by row>>8 with in-chunk LDS index sort (contiguous bbuf runs).
// CHUNK 3072 @ 512 threads -> 977 blocks = 3.8/CU (was 1.9, Occupancy 18%).
// pack: x = col | (row&255)<<18 ; y = val bits
// ---------------------------------------------------------------------------
__global__ __launch_bounds__(512) void k_bucket(const int* __restrict__ rows,
                                                const int* __restrict__ cols,
                                                const float* __restrict__ vals,
                                                int* __restrict__ bcnt,      // stride 16 (line-padded)
                                                int2* __restrict__ bbuf) {
    __shared__ u16 order[CHUNK];       // 6 KB sorted edge indices
    __shared__ int hist[NB], cur[NB], curbase[NB], gbase[NB];
    __shared__ int ws8[8];
    int tid = threadIdx.x, lane = tid & 63, w = tid >> 6;
    int start = blockIdx.x * CHUNK;
    int n = min(start + CHUNK, NNZ) - start;

    for (int i = tid; i < NB; i += 512) hist[i] = 0;
    __syncthreads();
    for (int i = tid; i < n; i += 512)
        atomicAdd(&hist[rows[start + i] >> 8], 1);
    __syncthreads();

    // exclusive scan of hist[0..NB), 512 threads, 2 rounds with carry
    int carry = 0;
    for (int base = 0; base < NB; base += 512) {
        int i = base + tid;
        int x = (i < NB) ? hist[i] : 0;
        int v = x;
#pragma unroll
        for (int off = 1; off < 64; off <<= 1) {
            int y = __shfl_up(v, off);
            if (lane >= off) v += y;
        }
        if (lane == 63) ws8[w] = v;
        __syncthreads();
        if (tid < 8) {
            int s = ws8[tid];
#pragma unroll
            for (int off = 1; off < 8; off <<= 1) {
                int y = __shfl_up(s, off);
                if (tid >= off) s += y;
            }
            ws8[tid] = s;
        }
        __syncthreads();
        int excl = carry + (w ? ws8[w - 1] : 0) + v - x;
        if (i < NB) { cur[i] = excl; curbase[i] = excl; }
        carry += ws8[7];
        __syncthreads();
    }

    // reserve global runs
    for (int i = tid; i < NB; i += 512) {
        int h = hist[i];
        gbase[i] = h ? atomicAdd(&bcnt[i * 16], h) : 0;
    }
    __syncthreads();

    // scatter indices into sorted order (LDS only)
    for (int i = tid; i < n; i += 512) {
        int b = rows[start + i] >> 8;
        int pos = atomicAdd(&cur[b], 1);
        order[pos] = (u16)i;
    }
    __syncthreads();

    // write pass: sorted order -> contiguous bbuf runs (coalesced)
    for (int j = tid; j < n; j += 512) {
        int i = order[j];
        int e = start + i;
        int r = rows[e];
        int b = r >> 8;
        int pos = gbase[b] + (j - curbase[b]);
        if (pos < BCAP)
            bbuf[(size_t)b * BCAP + pos] =
                make_int2(cols[e] | ((r & 255) << 18), __float_as_int(vals[e]));
    }
}

// ---------------------------------------------------------------------------
// Fused layer, one block per 256-row bucket, 512 threads (8 waves).
// Phase 1: stream edges (unroll x8), accumulate into LDS int tile via native
//   no-return ds_add_u32, fixed point 2^18.
//   BANK PERMUTATION: dim (8a+b) of row r stored at word
//     r*67 + 4a + (b>>1) + 32*(b&1)
//   -> each write instruction hits 8 DISTINCT banks stride-4 per edge-slot
//   (was 4 banks stride-8 2-way), slot collisions only mod 4 and 1-deep.
// Phase 2: MFMA dense: even dims at +0..3, odd dims at +32..35 per
//   (kk,quad) group; side(256x64) @ W(64x64 f16) + bias, leaky_relu, f16.
//   A[m=lane&15][k=quad*8+j], B[k][n=lane&15], C/D col=lane&15,row=quad*4+reg.
// LDS: 256*67*4 + 64*72*2 = 76 KB -> 2 blocks/CU.
// ---------------------------------------------------------------------------
__global__ __launch_bounds__(512) void k_fused(const int* __restrict__ bcnt,
                                               const int2* __restrict__ bbuf,
                                               const f16* __restrict__ ego_in,
                                               const float* __restrict__ W,
                                               const float* __restrict__ bias,
                                               u16* __restrict__ ego_out) {
    __shared__ int S[256 * SSTR];
    __shared__ f16 Wl[64 * 72];    // Wl[n][k], stride 72
    int tid = threadIdx.x;
    for (int i = tid; i < 256 * SSTR; i += 512) S[i] = 0;
    for (int i = tid; i < 4096; i += 512) {       // i = k*64 + n
        int k = i >> 6, n = i & 63;
        Wl[n * 72 + k] = (f16)W[i];
    }
    __syncthreads();

    int b = blockIdx.x;
    int cnt = min(bcnt[b * 16], BCAP);
    const int2* src = bbuf + (size_t)b * BCAP;
    int slot = tid >> 3;            // edge slot 0..63
    int d8   = tid & 7;             // dims 8*d8 .. 8*d8+7
    const char* egob = (const char*)ego_in;

    for (int it0 = 0; it0 < cnt; it0 += 512) {
        int2  pr[8];
        float mk[8];
        uint4 g[8];
#pragma unroll
        for (int u = 0; u < 8; ++u) {
            int ee = it0 + slot + u * 64;
            int ec = min(ee, cnt - 1);
            pr[u] = src[ec];
            mk[u] = (ee < cnt) ? SCALE : 0.f;
        }
#pragma unroll
        for (int u = 0; u < 8; ++u) {
            int col = pr[u].x & 0x3FFFF;
            g[u] = *(const uint4*)(egob + ((size_t)col << 7) + d8 * 16);
        }
#pragma unroll
        for (int u = 0; u < 8; ++u) {
            float vs = __int_as_float(pr[u].y) * mk[u];
            int rl = ((u32)pr[u].x) >> 18;
            float2 f0 = __half22float2(*(const __half2*)&g[u].x);
            float2 f1 = __half22float2(*(const __half2*)&g[u].y);
            float2 f2 = __half22float2(*(const __half2*)&g[u].z);
            float2 f3 = __half22float2(*(const __half2*)&g[u].w);
            // dim 8*d8+j -> word rl*67 + 4*d8 + (j>>1) + 32*(j&1)
            int* sp = &S[rl * SSTR + d8 * 4];
            atomicAdd(sp + 0,  (int)(vs * f0.x));   // j=0
            atomicAdd(sp + 32, (int)(vs * f0.y));   // j=1
            atomicAdd(sp + 1,  (int)(vs * f1.x));   // j=2
            atomicAdd(sp + 33, (int)(vs * f1.y));   // j=3
            atomicAdd(sp + 2,  (int)(vs * f2.x));   // j=4
            atomicAdd(sp + 34, (int)(vs * f2.y));   // j=5
            atomicAdd(sp + 3,  (int)(vs * f3.x));   // j=6
            atomicAdd(sp + 35, (int)(vs * f3.y));   // j=7
        }
    }
    __syncthreads();

    // Phase 2: MFMA epilogue. 8 waves x 2 m-tiles -> 256 rows.
    int lane = tid & 63, w = tid >> 6;
    int m = lane & 15, quad = lane >> 4;
    int rowbase = b * 256;
#pragma unroll
    for (int mt = 0; mt < 2; ++mt) {
        int m0 = w * 32 + mt * 16;
        f32x4 C[4] = {{0.f,0.f,0.f,0.f},{0.f,0.f,0.f,0.f},{0.f,0.f,0.f,0.f},{0.f,0.f,0.f,0.f}};
#pragma unroll
        for (int kk = 0; kk < 2; ++kk) {
            // dims kk*32 + quad*8 + j : even j=2c at base+c, odd at base+32+c
            const int* ap = &S[(m0 + m) * SSTR + kk * 16 + quad * 4];
            f16x8 A;
#pragma unroll
            for (int c = 0; c < 4; ++c) {
                A[2 * c]     = (f16)((float)ap[c]      * INVSC);
                A[2 * c + 1] = (f16)((float)ap[c + 32] * INVSC);
            }
#pragma unroll
            for (int nt = 0; nt < 4; ++nt) {
                f16x8 B = *(const f16x8*)&Wl[(nt * 16 + m) * 72 + kk * 32 + quad * 8];
                C[nt] = __builtin_amdgcn_mfma_f32_16x16x32_f16(A, B, C[nt], 0, 0, 0);
            }
        }
#pragma unroll
        for (int nt = 0; nt < 4; ++nt) {
            float bv = bias[nt * 16 + m];
#pragma unroll
            for (int r = 0; r < 4; ++r) {
                int orow = rowbase + m0 + quad * 4 + r;
                float o = C[nt][r] + bv;
                o = o > 0.f ? o : 0.2f * o;
                if (orow < NTOT) {
                    __half hh = __float2half(o);
                    ego_out[(size_t)orow * EMB + nt * 16 + m] = *(u16*)&hh;
                }
            }
        }
    }
}

// ---------------------------------------------------------------------------
// out[i][:] += l2norm(ego_f16[users[i]][:])
// ---------------------------------------------------------------------------
__global__ __launch_bounds__(256) void k_accum(const __half* __restrict__ ego,
                                               const int* __restrict__ users,
                                               float* __restrict__ out) {
    int t = blockIdx.x * 256 + threadIdx.x;
    int w = t >> 6, lane = t & 63;
    int u = users[w];
    float x = __half2float(ego[(size_t)u * EMB + lane]);
    float ss = x * x;
#pragma unroll
    for (int off = 32; off; off >>= 1) ss += __shfl_xor(ss, off);
    float n = sqrtf(ss);
    out[w * EMB + lane] += x / fmaxf(n, 1e-12f);
}

// ---------------------------------------------------------------------------
extern "C" void kernel_launch(void* const* d_in, const int* in_sizes, int n_in,
                              void* d_out, int out_size, void* d_ws, size_t ws_size,
                              hipStream_t stream) {
    const int*   users = (const int*)d_in[0];
    const int*   rows  = (const int*)d_in[1];
    const int*   cols  = (const int*)d_in[2];
    const float* vals  = (const float*)d_in[3];
    const float* ue    = (const float*)d_in[4];
    const float* ie    = (const float*)d_in[5];
    const float* Ws[3] = {(const float*)d_in[6], (const float*)d_in[8], (const float*)d_in[10]};
    const float* bs[3] = {(const float*)d_in[7], (const float*)d_in[9], (const float*)d_in[11]};
    float* out = (float*)d_out;

    // workspace layout (bytes, all 16B-aligned)
    char* p = (char*)d_ws;
    f16*  egoA  = (f16*)p;  p += (size_t)NTOT * EMB * 2;        // 19.2 MB
    f16*  egoB  = (f16*)p;  p += (size_t)NTOT * EMB * 2;        // 19.2 MB
    int2* bbuf  = (int2*)p; p += (size_t)NB * BCAP * 8;         // 26.4 MB
    int*  bcnt  = (int*)p;  p += (size_t)NB * 16 * 4;           // 37.5 KB (line-padded)

    hipMemsetAsync(bcnt, 0, (size_t)NB * 16 * 4, stream);
    k_init_ego<<<NTOT * EMB / 4 / 256, 256, 0, stream>>>(
        (const float4*)ue, (const float4*)ie, (uint2*)egoA);
    k_init_out<<<(BATCH * EMB) / 256, 256, 0, stream>>>(ue, users, out);

    // bucket by row>>8 (once, reused 3x)
    k_bucket<<<(NNZ + CHUNK - 1) / CHUNK, 512, 0, stream>>>(rows, cols, vals, bcnt, bbuf);

    // layer 3 only needs user rows -> only the first 196 buckets
    const int grids[3] = {NB, NB, (N_USER + 255) / 256};
    f16* bufs[2] = {egoA, egoB};
    for (int l = 0; l < 3; ++l) {
        const f16* src = bufs[l & 1];
        f16*       dst = bufs[(l + 1) & 1];
        k_fused<<<grids[l], 512, 0, stream>>>(bcnt, bbuf, src, Ws[l], bs[l], (u16*)dst);
        k_accum<<<(BATCH * EMB) / 256, 256, 0, stream>>>((const __half*)dst, users, out);
    }
}

// Round 11
// 368.844 us; speedup vs baseline: 1.0545x; 1.0545x over previous
//
#include <hip/hip_runtime.h>
#include <hip/hip_fp16.h>

#define N_USER 50000
#define N_ITEM 100000
#define NTOT   150000          // N_USER + N_ITEM
#define NNZ    3000000
#define EMB    64
#define BATCH  4096

#define BROWS  128             // rows per bucket
#define NB     1172            // ceil(150000/128)
#define BCAP   3008            // mean 2560, sd ~51 -> +8.8 sigma
#define CHUNK  6144            // edges per k_bucket block
#define SSTR   67              // LDS side-tile row stride (words)

#define SCALE  262144.0f       // 2^18 fixed-point scale
#define INVSC  (1.0f / 262144.0f)

typedef unsigned short u16;
typedef unsigned int   u32;
typedef _Float16 f16;
typedef f16   f16x8 __attribute__((ext_vector_type(8)));
typedef float f32x4 __attribute__((ext_vector_type(4)));

// ---------------------------------------------------------------------------
// ego(f16) = concat(user_emb, item_emb)
// ---------------------------------------------------------------------------
__global__ __launch_bounds__(256) void k_init_ego(const float4* __restrict__ ue,
                                                  const float4* __restrict__ ie,
                                                  uint2* __restrict__ ego) {
    int i = blockIdx.x * 256 + threadIdx.x;
    const int UF4 = N_USER * EMB / 4;     // 800000
    float4 f = (i < UF4) ? ue[i] : ie[i - UF4];
    __half2 h0 = __floats2half2_rn(f.x, f.y);
    __half2 h1 = __floats2half2_rn(f.z, f.w);
    ego[i] = make_uint2(*(u32*)&h0, *(u32*)&h1);
}

// ---------------------------------------------------------------------------
// out[i][:] = user_emb[users[i]][:]   (layer-0 contribution, exact fp32)
// ---------------------------------------------------------------------------
__global__ __launch_bounds__(256) void k_init_out(const float* __restrict__ ue,
                                                  const int* __restrict__ users,
                                                  float* __restrict__ out) {
    int t = blockIdx.x * 256 + threadIdx.x;
    int w = t >> 6, lane = t & 63;
    int u = users[w];
    out[w * EMB + lane] = ue[(size_t)u * EMB + lane];
}

// ---------------------------------------------------------------------------
// Bucket edges by row>>7. v3 (LDS-pack): scatter packed pairs into LDS at
// their bucket-sorted positions, then stream out coalesced. Removes the old
// order[]->rows/cols/vals re-gather chain from the write pass.
// pack: x = col | (row&127)<<18 ; y = val bits
// LDS: stage 48K + sbuck 12K + 4*NB*4=18.75K ~= 78.3 KB -> 2 blocks/CU.
// ---------------------------------------------------------------------------
__global__ __launch_bounds__(512) void k_bucket(const int* __restrict__ rows,
                                                const int* __restrict__ cols,
                                                const float* __restrict__ vals,
                                                int* __restrict__ bcnt,      // stride 16 (line-padded)
                                                int2* __restrict__ bbuf) {
    __shared__ int2 stage[CHUNK];      // 48 KB packed pairs, bucket-sorted
    __shared__ u16  sbuck[CHUNK];      // 12 KB bucket id per staged slot
    __shared__ int hist[NB], cur[NB], curbase[NB], gbase[NB];
    __shared__ int ws8[8];
    int tid = threadIdx.x, lane = tid & 63, w = tid >> 6;
    int start = blockIdx.x * CHUNK;
    int n = min(start + CHUNK, NNZ) - start;

    for (int i = tid; i < NB; i += 512) hist[i] = 0;
    __syncthreads();
    for (int i = tid; i < n; i += 512)
        atomicAdd(&hist[rows[start + i] >> 7], 1);
    __syncthreads();

    // exclusive scan of hist[0..NB), 512 threads, 3 rounds with carry
    int carry = 0;
    for (int base = 0; base < NB; base += 512) {
        int i = base + tid;
        int x = (i < NB) ? hist[i] : 0;
        int v = x;
#pragma unroll
        for (int off = 1; off < 64; off <<= 1) {
            int y = __shfl_up(v, off);
            if (lane >= off) v += y;
        }
        if (lane == 63) ws8[w] = v;
        __syncthreads();
        if (tid < 8) {
            int s = ws8[tid];
#pragma unroll
            for (int off = 1; off < 8; off <<= 1) {
                int y = __shfl_up(s, off);
                if (tid >= off) s += y;
            }
            ws8[tid] = s;
        }
        __syncthreads();
        int excl = carry + (w ? ws8[w - 1] : 0) + v - x;
        if (i < NB) { cur[i] = excl; curbase[i] = excl; }
        carry += ws8[7];
        __syncthreads();
    }

    // reserve global runs
    for (int i = tid; i < NB; i += 512) {
        int h = hist[i];
        gbase[i] = h ? atomicAdd(&bcnt[i * 16], h) : 0;
    }
    __syncthreads();

    // scatter packed pairs into LDS at sorted positions
    for (int i = tid; i < n; i += 512) {
        int e = start + i;
        int r = rows[e];
        int b = r >> 7;
        int pos = atomicAdd(&cur[b], 1);
        stage[pos] = make_int2(cols[e] | ((r & 127) << 18), __float_as_int(vals[e]));
        sbuck[pos] = (u16)b;
    }
    __syncthreads();

    // stream out: consecutive threads -> consecutive bbuf addresses per run
    for (int j = tid; j < n; j += 512) {
        int b = sbuck[j];
        int pos = gbase[b] + (j - curbase[b]);
        if (pos < BCAP)
            bbuf[(size_t)b * BCAP + pos] = stage[j];
    }
}

// ---------------------------------------------------------------------------
// Fused layer, one block per 128-row bucket, 512 threads (8 waves).
// Phase 1: stream edges (unroll x8), accumulate into LDS int tile via native
//   no-return ds_add_u32, fixed point 2^18. Bank map: dim d of row r at word
//   r*67 + (d>>1) + 32*(d&1).
// Phase 2: MFMA dense: side(128x64) @ W(64x64 f16) + bias, leaky_relu, f16.
//   A[m=lane&15][k=quad*8+j], B[k][n=lane&15], C/D col=lane&15,row=quad*4+reg.
// LDS: 128*67*4 + 64*72*2 = 43.5 KB -> 3 blocks/CU (was 2): +50% gather
// concurrency to hide L3 latency, more waves to overlap conflict replays.
// ---------------------------------------------------------------------------
__global__ __launch_bounds__(512) void k_fused(const int* __restrict__ bcnt,
                                               const int2* __restrict__ bbuf,
                                               const f16* __restrict__ ego_in,
                                               const float* __restrict__ W,
                                               const float* __restrict__ bias,
                                               u16* __restrict__ ego_out) {
    __shared__ int S[BROWS * SSTR];
    __shared__ f16 Wl[64 * 72];    // Wl[n][k], stride 72
    int tid = threadIdx.x;
    for (int i = tid; i < BROWS * SSTR; i += 512) S[i] = 0;
    for (int i = tid; i < 4096; i += 512) {       // i = k*64 + n
        int k = i >> 6, n = i & 63;
        Wl[n * 72 + k] = (f16)W[i];
    }
    __syncthreads();

    int b = blockIdx.x;
    int cnt = min(bcnt[b * 16], BCAP);
    const int2* src = bbuf + (size_t)b * BCAP;
    int slot = tid >> 3;            // edge slot 0..63
    int d8   = tid & 7;             // dims 8*d8 .. 8*d8+7
    const char* egob = (const char*)ego_in;

    for (int it0 = 0; it0 < cnt; it0 += 512) {
        int2  pr[8];
        float mk[8];
        uint4 g[8];
#pragma unroll
        for (int u = 0; u < 8; ++u) {
            int ee = it0 + slot + u * 64;
            int ec = min(ee, cnt - 1);
            pr[u] = src[ec];
            mk[u] = (ee < cnt) ? SCALE : 0.f;
        }
#pragma unroll
        for (int u = 0; u < 8; ++u) {
            int col = pr[u].x & 0x3FFFF;
            g[u] = *(const uint4*)(egob + ((size_t)col << 7) + d8 * 16);
        }
#pragma unroll
        for (int u = 0; u < 8; ++u) {
            float vs = __int_as_float(pr[u].y) * mk[u];
            int rl = ((u32)pr[u].x) >> 18;
            float2 f0 = __half22float2(*(const __half2*)&g[u].x);
            float2 f1 = __half22float2(*(const __half2*)&g[u].y);
            float2 f2 = __half22float2(*(const __half2*)&g[u].z);
            float2 f3 = __half22float2(*(const __half2*)&g[u].w);
            // dim 8*d8+j -> word rl*67 + 4*d8 + (j>>1) + 32*(j&1)
            int* sp = &S[rl * SSTR + d8 * 4];
            atomicAdd(sp + 0,  (int)(vs * f0.x));   // j=0
            atomicAdd(sp + 32, (int)(vs * f0.y));   // j=1
            atomicAdd(sp + 1,  (int)(vs * f1.x));   // j=2
            atomicAdd(sp + 33, (int)(vs * f1.y));   // j=3
            atomicAdd(sp + 2,  (int)(vs * f2.x));   // j=4
            atomicAdd(sp + 34, (int)(vs * f2.y));   // j=5
            atomicAdd(sp + 3,  (int)(vs * f3.x));   // j=6
            atomicAdd(sp + 35, (int)(vs * f3.y));   // j=7
        }
    }
    __syncthreads();

    // Phase 2: MFMA epilogue. 8 waves x 16 rows -> 128 rows.
    int lane = tid & 63, w = tid >> 6;
    int m = lane & 15, quad = lane >> 4;
    int rowbase = b * BROWS;
    int m0 = w * 16;
    f32x4 C[4] = {{0.f,0.f,0.f,0.f},{0.f,0.f,0.f,0.f},{0.f,0.f,0.f,0.f},{0.f,0.f,0.f,0.f}};
#pragma unroll
    for (int kk = 0; kk < 2; ++kk) {
        // dims kk*32 + quad*8 + j : even j=2c at base+c, odd at base+32+c
        const int* ap = &S[(m0 + m) * SSTR + kk * 16 + quad * 4];
        f16x8 A;
#pragma unroll
        for (int c = 0; c < 4; ++c) {
            A[2 * c]     = (f16)((float)ap[c]      * INVSC);
            A[2 * c + 1] = (f16)((float)ap[c + 32] * INVSC);
        }
#pragma unroll
        for (int nt = 0; nt < 4; ++nt) {
            f16x8 B = *(const f16x8*)&Wl[(nt * 16 + m) * 72 + kk * 32 + quad * 8];
            C[nt] = __builtin_amdgcn_mfma_f32_16x16x32_f16(A, B, C[nt], 0, 0, 0);
        }
    }
#pragma unroll
    for (int nt = 0; nt < 4; ++nt) {
        float bv = bias[nt * 16 + m];
#pragma unroll
        for (int r = 0; r < 4; ++r) {
            int orow = rowbase + m0 + quad * 4 + r;
            float o = C[nt][r] + bv;
            o = o > 0.f ? o : 0.2f * o;
            if (orow < NTOT) {
                __half hh = __float2half(o);
                ego_out[(size_t)orow * EMB + nt * 16 + m] = *(u16*)&hh;
            }
        }
    }
}

// ---------------------------------------------------------------------------
// out[i][:] += l2norm(ego_f16[users[i]][:])
// ---------------------------------------------------------------------------
__global__ __launch_bounds__(256) void k_accum(const __half* __restrict__ ego,
                                               const int* __restrict__ users,
                                               float* __restrict__ out) {
    int t = blockIdx.x * 256 + threadIdx.x;
    int w = t >> 6, lane = t & 63;
    int u = users[w];
    float x = __half2float(ego[(size_t)u * EMB + lane]);
    float ss = x * x;
#pragma unroll
    for (int off = 32; off; off >>= 1) ss += __shfl_xor(ss, off);
    float n = sqrtf(ss);
    out[w * EMB + lane] += x / fmaxf(n, 1e-12f);
}

// ---------------------------------------------------------------------------
extern "C" void kernel_launch(void* const* d_in, const int* in_sizes, int n_in,
                              void* d_out, int out_size, void* d_ws, size_t ws_size,
                              hipStream_t stream) {
    const int*   users = (const int*)d_in[0];
    const int*   rows  = (const int*)d_in[1];
    const int*   cols  = (const int*)d_in[2];
    const float* vals  = (const float*)d_in[3];
    const float* ue    = (const float*)d_in[4];
    const float* ie    = (const float*)d_in[5];
    const float* Ws[3] = {(const float*)d_in[6], (const float*)d_in[8], (const float*)d_in[10]};
    const float* bs[3] = {(const float*)d_in[7], (const float*)d_in[9], (const float*)d_in[11]};
    float* out = (float*)d_out;

    // workspace layout (bytes, all 16B-aligned)
    char* p = (char*)d_ws;
    f16*  egoA  = (f16*)p;  p += (size_t)NTOT * EMB * 2;        // 19.2 MB
    f16*  egoB  = (f16*)p;  p += (size_t)NTOT * EMB * 2;        // 19.2 MB
    int2* bbuf  = (int2*)p; p += (size_t)NB * BCAP * 8;         // 28.2 MB
    int*  bcnt  = (int*)p;  p += (size_t)NB * 16 * 4;           // 75 KB (line-padded)

    hipMemsetAsync(bcnt, 0, (size_t)NB * 16 * 4, stream);
    k_init_ego<<<NTOT * EMB / 4 / 256, 256, 0, stream>>>(
        (const float4*)ue, (const float4*)ie, (uint2*)egoA);
    k_init_out<<<(BATCH * EMB) / 256, 256, 0, stream>>>(ue, users, out);

    // bucket by row>>7 (once, reused 3x)
    k_bucket<<<(NNZ + CHUNK - 1) / CHUNK, 512, 0, stream>>>(rows, cols, vals, bcnt, bbuf);

    // layer 3 only needs user rows -> only the first 391 buckets
    const int grids[3] = {NB, NB, (N_USER + BROWS - 1) / BROWS};
    f16* bufs[2] = {egoA, egoB};
    for (int l = 0; l < 3; ++l) {
        const f16* src = bufs[l & 1];
        f16*       dst = bufs[(l + 1) & 1];
        k_fused<<<grids[l], 512, 0, stream>>>(bcnt, bbuf, src, Ws[l], bs[l], (u16*)dst);
        k_accum<<<(BATCH * EMB) / 256, 256, 0, stream>>>((const __half*)dst, users, out);
    }
}